// Round 15
// baseline (2705.849 us; speedup 1.0000x reference)
//
#include <hip/hip_runtime.h>
#include <math.h>

// GPT-2-ish forward: V=50257, C=1024, H=16, L=8, B=2, T=1024, D=64
#define V_ 50257
#define C_ 1024
#define H_ 16
#define L_ 8
#define B_ 2
#define T_ 1024
#define BT_ 2048
#define CC_ (C_*C_)
#define QLD_ 3072   // packed q|k|v row stride (bf16)

typedef unsigned short ushort_t;
using bf16x8 = __attribute__((ext_vector_type(8))) short;
using f32x4  = __attribute__((ext_vector_type(4))) float;

#define AS1 __attribute__((address_space(1)))
#define AS3 __attribute__((address_space(3)))
#define VMCNT0() asm volatile("s_waitcnt vmcnt(0)" ::: "memory")
#define LGKM0()  asm volatile("s_waitcnt lgkmcnt(0)" ::: "memory")
#define RBAR()   asm volatile("s_barrier" ::: "memory")

__device__ __forceinline__ ushort_t f2bf(float f){
  union { float f; unsigned u; } a; a.f = f;
  unsigned r = a.u + 0x7fffu + ((a.u >> 16) & 1u);   // RNE
  return (ushort_t)(r >> 16);
}

// pack 2 f32 -> 2 bf16 in one u32 (lo=a, hi=b), RNE, gfx950 native
__device__ __forceinline__ unsigned cvtpk_bf16(float a, float b){
  unsigned r;
  asm("v_cvt_pk_bf16_f32 %0, %1, %2" : "=v"(r) : "v"(a), "v"(b));
  return r;
}

__device__ __forceinline__ float wave_sum(float v){
  #pragma unroll
  for(int o=32;o>0;o>>=1) v += __shfl_down(v,o,64);
  return v;
}

// ---------------- fused weight conversion (one launch for everything) ----------------
__global__ __launch_bounds__(256) void cvt_all(
    const float* __restrict__ wq, const float* __restrict__ wk, const float* __restrict__ wv,
    const float* __restrict__ wp, const float* __restrict__ w1, const float* __restrict__ w2,
    const float* __restrict__ wh,
    ushort_t* __restrict__ dqkv, ushort_t* __restrict__ dp, ushort_t* __restrict__ d1,
    ushort_t* __restrict__ d2, ushort_t* __restrict__ dh, long n5)
{
  const long inner4 = (long)CC_/4;
  const long n1 = (long)L_*3*inner4;
  const long n2 = (long)L_*inner4;
  const long n3 = (long)L_*4*inner4;
  const long n4 = n3;
  const long c1 = n1, c2 = c1+n2, c3 = c2+n3, c4 = c3+n4, c5 = c4+n5;
  for(long i = (long)blockIdx.x*256 + threadIdx.x; i < c5; i += (long)gridDim.x*256){
    const float* s; ushort_t* d; long di;
    if(i < c1){
      long l = i / (3*inner4), r = i - l*3*inner4;
      int which = (int)(r / inner4);
      long rr = r - (long)which*inner4;
      s = (which==0 ? wq : which==1 ? wk : wv) + (l*inner4 + rr)*4;
      d = dqkv; di = i;
    } else if(i < c2){ long j = i-c1; s = wp + j*4; d = dp; di = j; }
    else if(i < c3){ long j = i-c2; s = w1 + j*4; d = d1; di = j; }
    else if(i < c4){ long j = i-c3; s = w2 + j*4; d = d2; di = j; }
    else           { long j = i-c4; s = wh + j*4; d = dh; di = j; }
    float4 v = *(const float4*)s;
    ushort4 o; o.x=f2bf(v.x); o.y=f2bf(v.y); o.z=f2bf(v.z); o.w=f2bf(v.w);
    ((ushort4*)d)[di] = o;
  }
}

__global__ __launch_bounds__(256) void pack_qkv_bias(const float* __restrict__ bq,
    const float* __restrict__ bk, const float* __restrict__ bv, float* __restrict__ dst){
  int i = blockIdx.x*256 + threadIdx.x;          // L*3072
  int l = i / QLD_, c = i - l*QLD_;
  float v;
  if(c < C_)            v = bq[l*C_ + c];
  else if(c < 2*C_)     v = bk[l*C_ + c - C_];
  else                  v = bv[l*C_ + c - 2*C_];
  dst[i] = v;
}

__global__ __launch_bounds__(256) void embed_kernel(const int* __restrict__ idx,
    const float* __restrict__ tok, const float* __restrict__ pos, float* __restrict__ x){
  int i = blockIdx.x*256 + threadIdx.x;
  int c = i & (C_-1); int bt = i >> 10; int t = bt & (T_-1);
  x[i] = tok[(size_t)idx[bt]*C_ + c] + pos[t*C_ + c];
}

// LayerNorm over C=1024; writes f32 (outF) or bf16 (outB). in==outF safe.
__global__ __launch_bounds__(256) void ln_kernel(const float* in, const float* __restrict__ w,
    const float* __restrict__ b, float* outF, ushort_t* outB){
  int row = blockIdx.x;
  const float* xr = in + (size_t)row*C_;
  float vals[4]; float sum=0.f, sq=0.f;
  #pragma unroll
  for(int l=0;l<4;l++){ float v = xr[threadIdx.x + l*256]; vals[l]=v; sum+=v; sq+=v*v; }
  __shared__ float r1[4], r2[4];
  float s1 = wave_sum(sum), s2 = wave_sum(sq);
  int wid = threadIdx.x>>6, lane = threadIdx.x&63;
  if(lane==0){ r1[wid]=s1; r2[wid]=s2; }
  __syncthreads();
  float tot  = r1[0]+r1[1]+r1[2]+r1[3];
  float tot2 = r2[0]+r2[1]+r2[2]+r2[3];
  float mu  = tot * (1.f/C_);
  float var = tot2 * (1.f/C_) - mu*mu;
  float inv = rsqrtf(var + 1e-5f);
  #pragma unroll
  for(int l=0;l<4;l++){
    int c = threadIdx.x + l*256;
    float v = (vals[l]-mu)*inv*w[c] + b[c];
    if(outB) outB[(size_t)row*C_ + c] = f2bf(v);
    else     outF[(size_t)row*C_ + c] = v;
  }
}

// ---------------- bf16 MFMA GEMM, 3-buffer depth-2 counted-vmcnt (head) ----------------
// R9-proven skeleton. BN=64 for head: 36KB LDS -> 4 blocks/CU (16 waves/CU TLP).
// grid (x = M/128, y = N/BN), M-fastest + XCD-bijective swizzle (nwg%8==0).
template<int BN>
__global__ __launch_bounds__(256) void gemm_mfma(
    const ushort_t* __restrict__ A, const ushort_t* __restrict__ W,
    const float* __restrict__ bias, const float* resid,
    float* outF, ushort_t* outB,
    int M, int N, int K, int act, int nt, int qs)
{
  constexpr int BM = 128;
  constexpr int NSB = BN/16;          // B-subtiles (4 or 8)
  constexpr int NBF = BN/32;          // B frags per wave (2 or 4)
  __shared__ __align__(16) short sA[3][8*512];
  __shared__ __align__(16) short sB[3][NSB*512];
  const int tid  = threadIdx.x;
  const int lane = tid & 63, wid = tid >> 6;
  const int wr = wid >> 1, wc = wid & 1;
  const int nwg = gridDim.x * gridDim.y;
  const int lid = blockIdx.x + gridDim.x * blockIdx.y;
  const int swz = (lid & 7) * (nwg >> 3) + (lid >> 3);
  const int m0 = (swz % gridDim.x) * BM, n0 = (swz / gridDim.x) * BN;
  const int r16 = lane & 15, kq = lane >> 4;

  auto stage = [&](int buf, int k0){
    #pragma unroll
    for(int s2=0; s2<2; ++s2){
      int s = wid*2 + s2;
      const ushort_t* g = A + (size_t)(m0 + s*16 + r16)*K + k0 + kq*8;
      __builtin_amdgcn_global_load_lds((const AS1 void*)g,
          (AS3 void*)&sA[buf][s*512], 16, 0, 0);
    }
    #pragma unroll
    for(int s2=0; s2<NSB/4; ++s2){
      int s = wid*(NSB/4) + s2;
      int gn = n0 + s*16 + r16; if(gn >= N) gn = N-1;
      const ushort_t* g = W + (size_t)gn*K + k0 + kq*8;
      __builtin_amdgcn_global_load_lds((const AS1 void*)g,
          (AS3 void*)&sB[buf][s*512], 16, 0, 0);
    }
  };

  f32x4 acc[4][NBF];
  #pragma unroll
  for(int i=0;i<4;i++)
    #pragma unroll
    for(int j=0;j<NBF;j++) acc[i][j] = (f32x4){0.f,0.f,0.f,0.f};

  const int NT = K >> 5;
  stage(0, 0); stage(1, 32); stage(2, 64);

  int cur = 0;
  for(int t=0; t<NT; ++t){
    if(t+2 < NT){
      if constexpr(BN==128) asm volatile("s_waitcnt vmcnt(8)" ::: "memory");
      else                  asm volatile("s_waitcnt vmcnt(6)" ::: "memory");
    } else if(t+1 < NT){
      if constexpr(BN==128) asm volatile("s_waitcnt vmcnt(4)" ::: "memory");
      else                  asm volatile("s_waitcnt vmcnt(3)" ::: "memory");
    } else {
      VMCNT0();
    }
    RBAR();                           // buf `cur` visible block-wide
    bf16x8 af[4], bfr[NBF];
    #pragma unroll
    for(int m=0;m<4;m++) af[m] = *(const bf16x8*)&sA[cur][(wr*4+m)*512 + lane*8];
    #pragma unroll
    for(int n=0;n<NBF;n++) bfr[n] = *(const bf16x8*)&sB[cur][(wc*NBF+n)*512 + lane*8];
    LGKM0();                          // own-wave reads complete
    RBAR();                           // all waves done reading `cur`
    if(t+3 < NT) stage(cur, (t+3)*32);
    #pragma unroll
    for(int m=0;m<4;m++)
      #pragma unroll
      for(int n=0;n<NBF;n++)
        acc[m][n] = __builtin_amdgcn_mfma_f32_16x16x32_bf16(af[m], bfr[n], acc[m][n], 0, 0, 0);
    cur = (cur==2) ? 0 : cur+1;
  }

  const int colb = n0 + wc*(BN/2);
  #pragma unroll
  for(int m=0;m<4;m++){
    int rowb = m0 + wr*64 + m*16 + kq*4;
    #pragma unroll
    for(int n=0;n<NBF;n++){
      int col = colb + n*16 + r16;
      if(col >= N) continue;
      float bv = bias ? bias[col] : 0.f;
      #pragma unroll
      for(int i=0;i<4;i++){
        int row = rowb + i;
        float v = acc[m][n][i] + bv;
        if(qs && col < C_) v *= 0.125f;
        if(act) v = 0.5f*v*(1.f + erff(v*0.70710678118654752f));
        if(resid) v += resid[(size_t)row*N + col];
        if(outB) outB[(size_t)row*N + col] = f2bf(v);
        else if(nt) __builtin_nontemporal_store(v, &outF[(size_t)row*N + col]);
        else outF[(size_t)row*N + col] = v;
      }
    }
  }
}

// ---------------- BM=64 BK=32 variant (QKV / fc1) ----------------
template<int BN>
__global__ __launch_bounds__(256) void gemm_s64(
    const ushort_t* __restrict__ A, const ushort_t* __restrict__ W,
    const float* __restrict__ bias, const float* resid,
    float* outF, ushort_t* outB,
    int M, int N, int K, int act, int qs)
{
  constexpr int NSB = BN/16;          // 4 or 8
  constexpr int NBF = BN/32;          // 2 or 4
  constexpr int LPW = 1 + NSB/4;      // loads per wave per stage (2 or 3)
  __shared__ __align__(16) short sA[3][4*512];
  __shared__ __align__(16) short sB[3][NSB*512];
  const int tid  = threadIdx.x;
  const int lane = tid & 63, wid = tid >> 6;
  const int wr = wid >> 1, wc = wid & 1;
  const int nwg = gridDim.x * gridDim.y;
  const int lid = blockIdx.x + gridDim.x * blockIdx.y;
  const int swz = (lid & 7) * (nwg >> 3) + (lid >> 3);
  const int m0 = (swz % gridDim.x) * 64, n0 = (swz / gridDim.x) * BN;
  const int r16 = lane & 15, kq = lane >> 4;

  auto stage = [&](int buf, int k0){
    {
      const ushort_t* g = A + (size_t)(m0 + wid*16 + r16)*K + k0 + kq*8;
      __builtin_amdgcn_global_load_lds((const AS1 void*)g,
          (AS3 void*)&sA[buf][wid*512], 16, 0, 0);
    }
    #pragma unroll
    for(int s2=0; s2<NSB/4; ++s2){
      int s = wid*(NSB/4) + s2;
      const ushort_t* g = W + (size_t)(n0 + s*16 + r16)*K + k0 + kq*8;
      __builtin_amdgcn_global_load_lds((const AS1 void*)g,
          (AS3 void*)&sB[buf][s*512], 16, 0, 0);
    }
  };

  f32x4 acc[2][NBF];
  #pragma unroll
  for(int i=0;i<2;i++)
    #pragma unroll
    for(int j=0;j<NBF;j++) acc[i][j] = (f32x4){0.f,0.f,0.f,0.f};

  const int NT = K >> 5;
  stage(0, 0); stage(1, 32); stage(2, 64);

  int cur = 0;
  for(int t=0; t<NT; ++t){
    if(t+2 < NT){
      if constexpr(LPW==2) asm volatile("s_waitcnt vmcnt(4)" ::: "memory");
      else                 asm volatile("s_waitcnt vmcnt(6)" ::: "memory");
    } else if(t+1 < NT){
      if constexpr(LPW==2) asm volatile("s_waitcnt vmcnt(2)" ::: "memory");
      else                 asm volatile("s_waitcnt vmcnt(3)" ::: "memory");
    } else {
      VMCNT0();
    }
    RBAR();
    bf16x8 af[2], bfr[NBF];
    #pragma unroll
    for(int m=0;m<2;m++) af[m] = *(const bf16x8*)&sA[cur][(wr*2+m)*512 + lane*8];
    #pragma unroll
    for(int n=0;n<NBF;n++) bfr[n] = *(const bf16x8*)&sB[cur][(wc*NBF+n)*512 + lane*8];
    LGKM0();
    RBAR();
    if(t+3 < NT) stage(cur, (t+3)*32);
    #pragma unroll
    for(int m=0;m<2;m++)
      #pragma unroll
      for(int n=0;n<NBF;n++)
        acc[m][n] = __builtin_amdgcn_mfma_f32_16x16x32_bf16(af[m], bfr[n], acc[m][n], 0, 0, 0);
    cur = (cur==2) ? 0 : cur+1;
  }

  const int colb = n0 + wc*(BN/2);
  #pragma unroll
  for(int m=0;m<2;m++){
    int rowb = m0 + wr*32 + m*16 + kq*4;
    #pragma unroll
    for(int n=0;n<NBF;n++){
      int col = colb + n*16 + r16;
      float bv = bias ? bias[col] : 0.f;
      #pragma unroll
      for(int i=0;i<4;i++){
        int row = rowb + i;
        float v = acc[m][n][i] + bv;
        if(qs && col < C_) v *= 0.125f;
        if(act) v = 0.5f*v*(1.f + erff(v*0.70710678118654752f));
        if(resid) v += resid[(size_t)row*N + col];
        if(outB) outB[(size_t)row*N + col] = f2bf(v);
        else outF[(size_t)row*N + col] = v;
      }
    }
  }
}

// ---------------- BM=64 BN=64 BK=64 variant (proj / fc2) ----------------
__global__ __launch_bounds__(256) void gemm_s64k64(
    const ushort_t* __restrict__ A, const ushort_t* __restrict__ W,
    const float* __restrict__ bias, const float* resid,
    float* outF, ushort_t* outB,
    int M, int N, int K)
{
  __shared__ __align__(16) short sA[3][2][4*512];   // [buf][khalf][sub*512+lane*8]
  __shared__ __align__(16) short sB[3][2][4*512];
  const int tid  = threadIdx.x;
  const int lane = tid & 63, wid = tid >> 6;
  const int wr = wid >> 1, wc = wid & 1;
  const int nwg = gridDim.x * gridDim.y;
  const int lid = blockIdx.x + gridDim.x * blockIdx.y;
  const int swz = (lid & 7) * (nwg >> 3) + (lid >> 3);
  const int m0 = (swz % gridDim.x) * 64, n0 = (swz / gridDim.x) * 64;
  const int r16 = lane & 15, kq = lane >> 4;

  auto stage = [&](int buf, int k0){              // 4 loads/wave
    #pragma unroll
    for(int h=0; h<2; ++h){
      const ushort_t* ga = A + (size_t)(m0 + wid*16 + r16)*K + k0 + h*32 + kq*8;
      __builtin_amdgcn_global_load_lds((const AS1 void*)ga,
          (AS3 void*)&sA[buf][h][wid*512], 16, 0, 0);
      const ushort_t* gb = W + (size_t)(n0 + wid*16 + r16)*K + k0 + h*32 + kq*8;
      __builtin_amdgcn_global_load_lds((const AS1 void*)gb,
          (AS3 void*)&sB[buf][h][wid*512], 16, 0, 0);
    }
  };

  f32x4 acc[2][2];
  #pragma unroll
  for(int i=0;i<2;i++)
    #pragma unroll
    for(int j=0;j<2;j++) acc[i][j] = (f32x4){0.f,0.f,0.f,0.f};

  const int NT = K >> 6;              // proj 16, fc2 64
  stage(0, 0); stage(1, 64); stage(2, 128);

  int cur = 0;
  for(int t=0; t<NT; ++t){
    if(t+2 < NT)      asm volatile("s_waitcnt vmcnt(8)" ::: "memory");
    else if(t+1 < NT) asm volatile("s_waitcnt vmcnt(4)" ::: "memory");
    else              VMCNT0();
    RBAR();
    bf16x8 af[2][2], bfr[2][2];       // [ks][m/n]
    #pragma unroll
    for(int ks=0; ks<2; ++ks){
      #pragma unroll
      for(int m=0;m<2;m++) af[ks][m] = *(const bf16x8*)&sA[cur][ks][(wr*2+m)*512 + lane*8];
      #pragma unroll
      for(int n=0;n<2;n++) bfr[ks][n] = *(const bf16x8*)&sB[cur][ks][(wc*2+n)*512 + lane*8];
    }
    LGKM0();
    RBAR();
    if(t+3 < NT) stage(cur, (t+3)*64);
    #pragma unroll
    for(int ks=0; ks<2; ++ks)
      #pragma unroll
      for(int m=0;m<2;m++)
        #pragma unroll
        for(int n=0;n<2;n++)
          acc[m][n] = __builtin_amdgcn_mfma_f32_16x16x32_bf16(af[ks][m], bfr[ks][n], acc[m][n], 0, 0, 0);
    cur = (cur==2) ? 0 : cur+1;
  }

  #pragma unroll
  for(int m=0;m<2;m++){
    int rowb = m0 + wr*32 + m*16 + kq*4;
    #pragma unroll
    for(int n=0;n<2;n++){
      int col = n0 + wc*32 + n*16 + r16;
      float bv = bias ? bias[col] : 0.f;
      #pragma unroll
      for(int i=0;i<4;i++){
        int row = rowb + i;
        float v = acc[m][n][i] + bv;
        if(resid) v += resid[(size_t)row*N + col];
        if(outB) outB[(size_t)row*N + col] = f2bf(v);
        else outF[(size_t)row*N + col] = v;
      }
    }
  }
}

// ---------------- fused flash attention (bf16 MFMA, KVBLK=64, async dbuf) ----------------
__global__ __launch_bounds__(256) void flash_kernel(const ushort_t* __restrict__ qkv,
    ushort_t* __restrict__ y){
  const int tid = threadIdx.x, lane = tid & 63, wid = tid >> 6;
  const int r16 = lane & 15, kq = lane >> 4;
  const int lid = blockIdx.x + 16*blockIdx.y;
  const int swz = (lid & 7)*64 + (lid >> 3);
  const int qt = 15 - (swz & 15), bh = swz >> 4;   // descending-qt (LPT)
  const int b = bh >> 4, h = bh & 15;
  const int q0 = qt*64, qw0 = q0 + wid*16;
  const int qa = qw0 + r16;

  __shared__ __align__(16) short Kt[2][8][512];
  __shared__ __align__(16) short VT[2][64][72];
  __shared__ __align__(16) short Pl[4][16][72];
  __shared__ __align__(16) short Ol[4][16][72];

  const size_t rowQ = (size_t)(b*T_ + qa)*QLD_ + h*64 + kq*8;
  bf16x8 qf0 = *(const bf16x8*)(qkv + rowQ);
  bf16x8 qf1 = *(const bf16x8*)(qkv + rowQ + 32);

  auto stageK = [&](int buf, int jt){
    #pragma unroll
    for(int s2=0;s2<2;s2++){
      int s = wid*2 + s2;
      const ushort_t* g = qkv + (size_t)(b*T_ + jt*64 + (s>>1)*16 + r16)*QLD_
                          + C_ + h*64 + (s&1)*32 + kq*8;
      __builtin_amdgcn_global_load_lds((const AS1 void*)g,
          (AS3 void*)&Kt[buf][s][lane*8], 16, 0, 0);
    }
  };

  f32x4 acc[4];
  #pragma unroll
  for(int t=0;t<4;t++) acc[t] = (f32x4){0.f,0.f,0.f,0.f};
  float m_r = -INFINITY, l_r = 0.f;

  {
    stageK(0, 0);
    const ushort_t* vg = qkv + (size_t)(b*T_ + lane)*QLD_ + 2*C_ + h*64;
    bf16x8 va = *(const bf16x8*)(vg + wid*8);
    bf16x8 vb = *(const bf16x8*)(vg + 32 + wid*8);
    VMCNT0();
    #pragma unroll
    for(int j=0;j<8;j++){ VT[0][wid*8+j][lane]=va[j]; VT[0][32+wid*8+j][lane]=vb[j]; }
    __syncthreads();
  }

  const int njt = qt + 1;
  for(int jt=0; jt<njt; ++jt){
    const int cur = jt & 1;
    const bool more = (jt+1) < njt;
    bf16x8 vr0, vr1;
    if(more){
      stageK(cur^1, jt+1);
      const ushort_t* vg = qkv + (size_t)(b*T_ + (jt+1)*64 + lane)*QLD_ + 2*C_ + h*64;
      vr0 = *(const bf16x8*)(vg + wid*8);
      vr1 = *(const bf16x8*)(vg + 32 + wid*8);
    }

    f32x4 st[4];
    __builtin_amdgcn_s_setprio(1);
    #pragma unroll
    for(int kr=0;kr<4;kr++){
      st[kr] = (f32x4){0.f,0.f,0.f,0.f};
      st[kr] = __builtin_amdgcn_mfma_f32_16x16x32_bf16(*(const bf16x8*)&Kt[cur][kr*2+0][lane*8], qf0, st[kr], 0,0,0);
      st[kr] = __builtin_amdgcn_mfma_f32_16x16x32_bf16(*(const bf16x8*)&Kt[cur][kr*2+1][lane*8], qf1, st[kr], 0,0,0);
    }
    __builtin_amdgcn_s_setprio(0);

    float vals[16];
    if(jt == njt-1){
      #pragma unroll
      for(int kr=0;kr<4;kr++)
        #pragma unroll
        for(int i=0;i<4;i++){
          int ka = jt*64 + kr*16 + 4*kq + i;
          vals[kr*4+i] = (ka <= qa) ? st[kr][i] : -INFINITY;
        }
    } else {
      #pragma unroll
      for(int kr=0;kr<4;kr++)
        #pragma unroll
        for(int i=0;i<4;i++) vals[kr*4+i] = st[kr][i];
    }
    float t8[8];
    #pragma unroll
    for(int i=0;i<8;i++) t8[i] = fmaxf(vals[i], vals[i+8]);
    float t4a = fmaxf(t8[0],t8[4]), t4b = fmaxf(t8[1],t8[5]);
    float t4c = fmaxf(t8[2],t8[6]), t4d = fmaxf(t8[3],t8[7]);
    float pmax = fmaxf(fmaxf(t4a,t4b), fmaxf(t4c,t4d));
    pmax = fmaxf(pmax, __shfl_xor(pmax, 16, 64));
    pmax = fmaxf(pmax, __shfl_xor(pmax, 32, 64));

    if(!__all(pmax - m_r <= 8.f)){
      float mnew = fmaxf(m_r, pmax);
      float alpha = __expf(m_r - mnew);
      l_r *= alpha;
      #pragma unroll
      for(int t=0;t<4;t++)
        #pragma unroll
        for(int j=0;j<4;j++) acc[t][j] *= alpha;
      m_r = mnew;
    }

    float ps = 0.f;
    #pragma unroll
    for(int kr=0;kr<4;kr++){
      float p0 = __expf(vals[kr*4+0]-m_r), p1 = __expf(vals[kr*4+1]-m_r);
      float p2 = __expf(vals[kr*4+2]-m_r), p3 = __expf(vals[kr*4+3]-m_r);
      ps += (p0+p1)+(p2+p3);
      *(unsigned*)&Pl[wid][r16][kr*16 + 4*kq]     = cvtpk_bf16(p0, p1);
      *(unsigned*)&Pl[wid][r16][kr*16 + 4*kq + 2] = cvtpk_bf16(p2, p3);
    }
    ps += __shfl_xor(ps, 16, 64);
    ps += __shfl_xor(ps, 32, 64);
    l_r += ps;

    union { bf16x8 v8; uint2 u2[2]; } pf, vf;
    __builtin_amdgcn_s_setprio(1);
    #pragma unroll
    for(int ks2=0; ks2<2; ks2++){
      pf.u2[0] = *(const uint2*)&Pl[wid][r16][ks2*32 + kq*8];
      pf.u2[1] = *(const uint2*)&Pl[wid][r16][ks2*32 + kq*8 + 4];
      #pragma unroll
      for(int db=0; db<4; db++){
        vf.u2[0] = *(const uint2*)&VT[cur][16*db + r16][ks2*32 + kq*8];
        vf.u2[1] = *(const uint2*)&VT[cur][16*db + r16][ks2*32 + kq*8 + 4];
        acc[db] = __builtin_amdgcn_mfma_f32_16x16x32_bf16(vf.v8, pf.v8, acc[db], 0,0,0);
      }
    }
    __builtin_amdgcn_s_setprio(0);

    if(more){
      VMCNT0();
      #pragma unroll
      for(int j=0;j<8;j++){ VT[cur^1][wid*8+j][lane]=vr0[j]; VT[cur^1][32+wid*8+j][lane]=vr1[j]; }
    }
    __syncthreads();
  }

  float linv = 1.f / l_r;
  #pragma unroll
  for(int db=0; db<4; db++)
    #pragma unroll
    for(int i=0;i<4;i++)
      Ol[wid][r16][16*db + 4*kq + i] = (short)f2bf(acc[db][i]*linv);
  int q = lane >> 2, c0 = (lane & 3)*16;
  const short* src = &Ol[wid][q][c0];
  uint2 a0 = *(const uint2*)(src+0), a1 = *(const uint2*)(src+4);
  uint2 a2 = *(const uint2*)(src+8), a3 = *(const uint2*)(src+12);
  ushort_t* dst = y + (size_t)(b*T_ + qw0 + q)*C_ + h*64 + c0;
  uint4 w0 = {a0.x, a0.y, a1.x, a1.y}, w1 = {a2.x, a2.y, a3.x, a3.y};
  *(uint4*)(dst+0) = w0;
  *(uint4*)(dst+8) = w1;
}

// ---------------- f32 GEMM fallback (head only, if ws too small) ----------------
__global__ __launch_bounds__(256) void gemm_nt(const float* __restrict__ A, const float* __restrict__ W,
    const float* __restrict__ bias, const float* resid, float* Cm,
    int M, int N, int K, int act){
  __shared__ float As[16][68];
  __shared__ float Bs[16][68];
  int m0 = blockIdx.y*64, n0 = blockIdx.x*64;
  int tid = threadIdx.x;
  int tx = tid & 15, ty = tid >> 4;
  float acc[4][4] = {};
  for(int k0=0;k0<K;k0+=16){
    #pragma unroll
    for(int l=0;l<4;l++){
      int li = tid + l*256;
      int r = li >> 4, c = li & 15;
      int gm = m0 + r, gn = n0 + r, gk = k0 + c;
      As[c][r] = (gm<M) ? A[(size_t)gm*K + gk] : 0.f;
      Bs[c][r] = (gn<N) ? W[(size_t)gn*K + gk] : 0.f;
    }
    __syncthreads();
    #pragma unroll
    for(int k=0;k<16;k++){
      float4 av = *(const float4*)&As[k][ty*4];
      float4 bv = *(const float4*)&Bs[k][tx*4];
      float a[4] = {av.x, av.y, av.z, av.w};
      float b4[4] = {bv.x, bv.y, bv.z, bv.w};
      #pragma unroll
      for(int i=0;i<4;i++)
        #pragma unroll
        for(int j=0;j<4;j++)
          acc[i][j] = fmaf(a[i], b4[j], acc[i][j]);
    }
    __syncthreads();
  }
  #pragma unroll
  for(int i=0;i<4;i++){
    int m = m0 + ty*4 + i; if(m>=M) continue;
    #pragma unroll
    for(int j=0;j<4;j++){
      int n = n0 + tx*4 + j; if(n>=N) continue;
      float v = acc[i][j];
      if(bias) v += bias[n];
      if(act)  v = 0.5f*v*(1.f + erff(v*0.70710678118654752f));
      if(resid) v += resid[(size_t)m*N + n];
      Cm[(size_t)m*N + n] = v;
    }
  }
}

extern "C" void kernel_launch(void* const* d_in, const int* in_sizes, int n_in,
                              void* d_out, int out_size, void* d_ws, size_t ws_size,
                              hipStream_t stream) {
  const int*   idx  = (const int*)  d_in[0];
  const float* tok  = (const float*)d_in[1];
  const float* pos  = (const float*)d_in[2];
  const float* Wq   = (const float*)d_in[3];
  const float* bq   = (const float*)d_in[4];
  const float* Wk   = (const float*)d_in[5];
  const float* bk   = (const float*)d_in[6];
  const float* Wv   = (const float*)d_in[7];
  const float* bv   = (const float*)d_in[8];
  const float* Wp   = (const float*)d_in[9];
  const float* bp   = (const float*)d_in[10];
  const float* ln1w = (const float*)d_in[11];
  const float* ln1b = (const float*)d_in[12];
  const float* ln2w = (const float*)d_in[13];
  const float* ln2b = (const float*)d_in[14];
  const float* W1   = (const float*)d_in[15];
  const float* b1   = (const float*)d_in[16];
  const float* W2   = (const float*)d_in[17];
  const float* b2   = (const float*)d_in[18];
  const float* lnfw = (const float*)d_in[19];
  const float* lnfb = (const float*)d_in[20];
  const float* headw= (const float*)d_in[21];

  float* out = (float*)d_out;
  ushort_t* qkvb = (ushort_t*)(out);                  //  6,291,456 bf16
  ushort_t* hb   = (ushort_t*)(out + 3145728);        //  2,097,152 bf16
  ushort_t* yb   = (ushort_t*)(out + 4194304);        //  2,097,152 bf16
  ushort_t* mb   = (ushort_t*)(out + 5242880);        //  8,388,608 bf16
  ushort_t* wqkv = (ushort_t*)(out + 9437184);        // 25,165,824 bf16
  ushort_t* wpb  = (ushort_t*)(out + 22020096);       //  8,388,608 bf16
  ushort_t* w1b  = (ushort_t*)(out + 26214400);       // 33,554,432 bf16
  ushort_t* w2b  = (ushort_t*)(out + 42991616);       // 33,554,432 bf16
  float*    bqkv = out + 59768832;                    //     24,576 f
  float*    x    = (float*)d_ws;
  ushort_t* xb   = (ushort_t*)((float*)d_ws + 2097152);
  ushort_t* whb  = (ushort_t*)((float*)d_ws + 3145728);
  const bool big = ws_size >= (size_t)28877312 * 4;

  cvt_all<<<4096,256,0,stream>>>(Wq, Wk, Wv, Wp, W1, W2, headw,
      wqkv, wpb, w1b, w2b, whb, big ? (long)V_*C_/4 : 0);
  pack_qkv_bias<<<L_*QLD_/256,256,0,stream>>>(bq, bk, bv, bqkv);

  embed_kernel<<<BT_*C_/256, 256, 0, stream>>>(idx, tok, pos, x);

  for(int l=0;l<L_;l++){
    ln_kernel<<<BT_,256,0,stream>>>(x, ln1w + l*C_, ln1b + l*C_, nullptr, hb);
    gemm_s64<128><<<dim3(BT_/64, QLD_/128),256,0,stream>>>(hb, wqkv + (size_t)l*3*CC_,
        bqkv + l*QLD_, nullptr, nullptr, qkvb, BT_, QLD_, C_, 0, 1);
    flash_kernel<<<dim3(T_/64, B_*H_),256,0,stream>>>(qkvb, yb);
    gemm_s64k64<<<dim3(BT_/64, C_/64),256,0,stream>>>(yb, wpb + (size_t)l*CC_,
        bp + l*C_, x, x, nullptr, BT_, C_, C_);
    ln_kernel<<<BT_,256,0,stream>>>(x, ln2w + l*C_, ln2b + l*C_, nullptr, hb);
    gemm_s64<128><<<dim3(BT_/64, 4*C_/128),256,0,stream>>>(hb, w1b + (size_t)l*4*CC_,
        b1 + (size_t)l*4*C_, nullptr, nullptr, mb, BT_, 4*C_, C_, 1, 0);
    gemm_s64k64<<<dim3(BT_/64, C_/64),256,0,stream>>>(mb, w2b + (size_t)l*4*CC_,
        b2 + l*C_, x, x, nullptr, BT_, C_, 4*C_);
  }

  if(big){
    ln_kernel<<<BT_,256,0,stream>>>(x, lnfw, lnfb, nullptr, xb);
    // BN=64 head: 36KB LDS -> 4 blocks/CU; grid 16 x 786 = 12576 (%8==0)
    gemm_mfma<64><<<dim3(BT_/128, (V_+63)/64),256,0,stream>>>(xb, whb,
        nullptr, nullptr, out, nullptr, BT_, V_, C_, 0, 1, 0);
  } else {
    ln_kernel<<<BT_,256,0,stream>>>(x, lnfw, lnfb, x, nullptr);
    gemm_nt<<<dim3((V_+63)/64, BT_/64),256,0,stream>>>(x, headw, nullptr, nullptr, out,
                                                       BT_, V_, C_, 0);
  }
}

// Round 16
// 2585.632 us; speedup vs baseline: 1.0465x; 1.0465x over previous
//
#include <hip/hip_runtime.h>
#include <math.h>

// GPT-2-ish forward: V=50257, C=1024, H=16, L=8, B=2, T=1024, D=64
#define V_ 50257
#define C_ 1024
#define H_ 16
#define L_ 8
#define B_ 2
#define T_ 1024
#define BT_ 2048
#define CC_ (C_*C_)
#define QLD_ 3072   // packed q|k|v row stride (bf16)

typedef unsigned short ushort_t;
using bf16x8 = __attribute__((ext_vector_type(8))) short;
using f32x4  = __attribute__((ext_vector_type(4))) float;

#define AS1 __attribute__((address_space(1)))
#define AS3 __attribute__((address_space(3)))
#define VMCNT0() asm volatile("s_waitcnt vmcnt(0)" ::: "memory")
#define LGKM0()  asm volatile("s_waitcnt lgkmcnt(0)" ::: "memory")
#define RBAR()   asm volatile("s_barrier" ::: "memory")

__device__ __forceinline__ ushort_t f2bf(float f){
  union { float f; unsigned u; } a; a.f = f;
  unsigned r = a.u + 0x7fffu + ((a.u >> 16) & 1u);   // RNE
  return (ushort_t)(r >> 16);
}

// pack 2 f32 -> 2 bf16 in one u32 (lo=a, hi=b), RNE, gfx950 native
__device__ __forceinline__ unsigned cvtpk_bf16(float a, float b){
  unsigned r;
  asm("v_cvt_pk_bf16_f32 %0, %1, %2" : "=v"(r) : "v"(a), "v"(b));
  return r;
}

__device__ __forceinline__ float wave_sum(float v){
  #pragma unroll
  for(int o=32;o>0;o>>=1) v += __shfl_down(v,o,64);
  return v;
}

// ---------------- fused weight conversion (one launch for everything) ----------------
__global__ __launch_bounds__(256) void cvt_all(
    const float* __restrict__ wq, const float* __restrict__ wk, const float* __restrict__ wv,
    const float* __restrict__ wp, const float* __restrict__ w1, const float* __restrict__ w2,
    const float* __restrict__ wh,
    ushort_t* __restrict__ dqkv, ushort_t* __restrict__ dp, ushort_t* __restrict__ d1,
    ushort_t* __restrict__ d2, ushort_t* __restrict__ dh, long n5)
{
  const long inner4 = (long)CC_/4;
  const long n1 = (long)L_*3*inner4;
  const long n2 = (long)L_*inner4;
  const long n3 = (long)L_*4*inner4;
  const long n4 = n3;
  const long c1 = n1, c2 = c1+n2, c3 = c2+n3, c4 = c3+n4, c5 = c4+n5;
  for(long i = (long)blockIdx.x*256 + threadIdx.x; i < c5; i += (long)gridDim.x*256){
    const float* s; ushort_t* d; long di;
    if(i < c1){
      long l = i / (3*inner4), r = i - l*3*inner4;
      int which = (int)(r / inner4);
      long rr = r - (long)which*inner4;
      s = (which==0 ? wq : which==1 ? wk : wv) + (l*inner4 + rr)*4;
      d = dqkv; di = i;
    } else if(i < c2){ long j = i-c1; s = wp + j*4; d = dp; di = j; }
    else if(i < c3){ long j = i-c2; s = w1 + j*4; d = d1; di = j; }
    else if(i < c4){ long j = i-c3; s = w2 + j*4; d = d2; di = j; }
    else           { long j = i-c4; s = wh + j*4; d = dh; di = j; }
    float4 v = *(const float4*)s;
    ushort4 o; o.x=f2bf(v.x); o.y=f2bf(v.y); o.z=f2bf(v.z); o.w=f2bf(v.w);
    ((ushort4*)d)[di] = o;
  }
}

__global__ __launch_bounds__(256) void pack_qkv_bias(const float* __restrict__ bq,
    const float* __restrict__ bk, const float* __restrict__ bv, float* __restrict__ dst){
  int i = blockIdx.x*256 + threadIdx.x;          // L*3072
  int l = i / QLD_, c = i - l*QLD_;
  float v;
  if(c < C_)            v = bq[l*C_ + c];
  else if(c < 2*C_)     v = bk[l*C_ + c - C_];
  else                  v = bv[l*C_ + c - 2*C_];
  dst[i] = v;
}

__global__ __launch_bounds__(256) void embed_kernel(const int* __restrict__ idx,
    const float* __restrict__ tok, const float* __restrict__ pos, float* __restrict__ x){
  int i = blockIdx.x*256 + threadIdx.x;
  int c = i & (C_-1); int bt = i >> 10; int t = bt & (T_-1);
  x[i] = tok[(size_t)idx[bt]*C_ + c] + pos[t*C_ + c];
}

// LayerNorm over C=1024; writes f32 (outF) or bf16 (outB). in==outF safe.
__global__ __launch_bounds__(256) void ln_kernel(const float* in, const float* __restrict__ w,
    const float* __restrict__ b, float* outF, ushort_t* outB){
  int row = blockIdx.x;
  const float* xr = in + (size_t)row*C_;
  float vals[4]; float sum=0.f, sq=0.f;
  #pragma unroll
  for(int l=0;l<4;l++){ float v = xr[threadIdx.x + l*256]; vals[l]=v; sum+=v; sq+=v*v; }
  __shared__ float r1[4], r2[4];
  float s1 = wave_sum(sum), s2 = wave_sum(sq);
  int wid = threadIdx.x>>6, lane = threadIdx.x&63;
  if(lane==0){ r1[wid]=s1; r2[wid]=s2; }
  __syncthreads();
  float tot  = r1[0]+r1[1]+r1[2]+r1[3];
  float tot2 = r2[0]+r2[1]+r2[2]+r2[3];
  float mu  = tot * (1.f/C_);
  float var = tot2 * (1.f/C_) - mu*mu;
  float inv = rsqrtf(var + 1e-5f);
  #pragma unroll
  for(int l=0;l<4;l++){
    int c = threadIdx.x + l*256;
    float v = (vals[l]-mu)*inv*w[c] + b[c];
    if(outB) outB[(size_t)row*C_ + c] = f2bf(v);
    else     outF[(size_t)row*C_ + c] = v;
  }
}

// ---------------- bf16 MFMA GEMM, 3-buffer depth-2 counted-vmcnt (head) ----------------
// R9-proven config: triple-buffered LDS (49 KB -> 3 blocks/CU), prefetch dist 2.
// grid (x = M/128, y = N/BN), M-fastest + XCD-bijective swizzle (nwg%8==0).
template<int BN>
__global__ __launch_bounds__(256) void gemm_mfma(
    const ushort_t* __restrict__ A, const ushort_t* __restrict__ W,
    const float* __restrict__ bias, const float* resid,
    float* outF, ushort_t* outB,
    int M, int N, int K, int act, int nt, int qs)
{
  constexpr int BM = 128;
  constexpr int NSB = BN/16;          // B-subtiles (4 or 8)
  constexpr int NBF = BN/32;          // B frags per wave (2 or 4)
  __shared__ __align__(16) short sA[3][8*512];
  __shared__ __align__(16) short sB[3][NSB*512];
  const int tid  = threadIdx.x;
  const int lane = tid & 63, wid = tid >> 6;
  const int wr = wid >> 1, wc = wid & 1;
  const int nwg = gridDim.x * gridDim.y;
  const int lid = blockIdx.x + gridDim.x * blockIdx.y;
  const int swz = (lid & 7) * (nwg >> 3) + (lid >> 3);
  const int m0 = (swz % gridDim.x) * BM, n0 = (swz / gridDim.x) * BN;
  const int r16 = lane & 15, kq = lane >> 4;

  auto stage = [&](int buf, int k0){
    #pragma unroll
    for(int s2=0; s2<2; ++s2){
      int s = wid*2 + s2;
      const ushort_t* g = A + (size_t)(m0 + s*16 + r16)*K + k0 + kq*8;
      __builtin_amdgcn_global_load_lds((const AS1 void*)g,
          (AS3 void*)&sA[buf][s*512], 16, 0, 0);
    }
    #pragma unroll
    for(int s2=0; s2<NSB/4; ++s2){
      int s = wid*(NSB/4) + s2;
      int gn = n0 + s*16 + r16; if(gn >= N) gn = N-1;
      const ushort_t* g = W + (size_t)gn*K + k0 + kq*8;
      __builtin_amdgcn_global_load_lds((const AS1 void*)g,
          (AS3 void*)&sB[buf][s*512], 16, 0, 0);
    }
  };

  f32x4 acc[4][NBF];
  #pragma unroll
  for(int i=0;i<4;i++)
    #pragma unroll
    for(int j=0;j<NBF;j++) acc[i][j] = (f32x4){0.f,0.f,0.f,0.f};

  const int NT = K >> 5;
  stage(0, 0); stage(1, 32); stage(2, 64);

  int cur = 0;
  for(int t=0; t<NT; ++t){
    if(t+2 < NT){
      if constexpr(BN==128) asm volatile("s_waitcnt vmcnt(8)" ::: "memory");
      else                  asm volatile("s_waitcnt vmcnt(6)" ::: "memory");
    } else if(t+1 < NT){
      if constexpr(BN==128) asm volatile("s_waitcnt vmcnt(4)" ::: "memory");
      else                  asm volatile("s_waitcnt vmcnt(3)" ::: "memory");
    } else {
      VMCNT0();
    }
    RBAR();                           // buf `cur` visible block-wide
    bf16x8 af[4], bfr[NBF];
    #pragma unroll
    for(int m=0;m<4;m++) af[m] = *(const bf16x8*)&sA[cur][(wr*4+m)*512 + lane*8];
    #pragma unroll
    for(int n=0;n<NBF;n++) bfr[n] = *(const bf16x8*)&sB[cur][(wc*NBF+n)*512 + lane*8];
    LGKM0();                          // own-wave reads complete
    RBAR();                           // all waves done reading `cur`
    if(t+3 < NT) stage(cur, (t+3)*32);
    #pragma unroll
    for(int m=0;m<4;m++)
      #pragma unroll
      for(int n=0;n<NBF;n++)
        acc[m][n] = __builtin_amdgcn_mfma_f32_16x16x32_bf16(af[m], bfr[n], acc[m][n], 0, 0, 0);
    cur = (cur==2) ? 0 : cur+1;
  }

  const int colb = n0 + wc*(BN/2);
  #pragma unroll
  for(int m=0;m<4;m++){
    int rowb = m0 + wr*64 + m*16 + kq*4;
    #pragma unroll
    for(int n=0;n<NBF;n++){
      int col = colb + n*16 + r16;
      if(col >= N) continue;
      float bv = bias ? bias[col] : 0.f;
      #pragma unroll
      for(int i=0;i<4;i++){
        int row = rowb + i;
        float v = acc[m][n][i] + bv;
        if(qs && col < C_) v *= 0.125f;
        if(act) v = 0.5f*v*(1.f + erff(v*0.70710678118654752f));
        if(resid) v += resid[(size_t)row*N + col];
        if(outB) outB[(size_t)row*N + col] = f2bf(v);
        else if(nt) __builtin_nontemporal_store(v, &outF[(size_t)row*N + col]);
        else outF[(size_t)row*N + col] = v;
      }
    }
  }
}

// ---------------- BM=64 BK=32 variant (QKV / fc1) ----------------
template<int BN>
__global__ __launch_bounds__(256) void gemm_s64(
    const ushort_t* __restrict__ A, const ushort_t* __restrict__ W,
    const float* __restrict__ bias, const float* resid,
    float* outF, ushort_t* outB,
    int M, int N, int K, int act, int qs)
{
  constexpr int NSB = BN/16;          // 4 or 8
  constexpr int NBF = BN/32;          // 2 or 4
  constexpr int LPW = 1 + NSB/4;      // loads per wave per stage (2 or 3)
  __shared__ __align__(16) short sA[3][4*512];
  __shared__ __align__(16) short sB[3][NSB*512];
  const int tid  = threadIdx.x;
  const int lane = tid & 63, wid = tid >> 6;
  const int wr = wid >> 1, wc = wid & 1;
  const int nwg = gridDim.x * gridDim.y;
  const int lid = blockIdx.x + gridDim.x * blockIdx.y;
  const int swz = (lid & 7) * (nwg >> 3) + (lid >> 3);
  const int m0 = (swz % gridDim.x) * 64, n0 = (swz / gridDim.x) * BN;
  const int r16 = lane & 15, kq = lane >> 4;

  auto stage = [&](int buf, int k0){
    {
      const ushort_t* g = A + (size_t)(m0 + wid*16 + r16)*K + k0 + kq*8;
      __builtin_amdgcn_global_load_lds((const AS1 void*)g,
          (AS3 void*)&sA[buf][wid*512], 16, 0, 0);
    }
    #pragma unroll
    for(int s2=0; s2<NSB/4; ++s2){
      int s = wid*(NSB/4) + s2;
      const ushort_t* g = W + (size_t)(n0 + s*16 + r16)*K + k0 + kq*8;
      __builtin_amdgcn_global_load_lds((const AS1 void*)g,
          (AS3 void*)&sB[buf][s*512], 16, 0, 0);
    }
  };

  f32x4 acc[2][NBF];
  #pragma unroll
  for(int i=0;i<2;i++)
    #pragma unroll
    for(int j=0;j<NBF;j++) acc[i][j] = (f32x4){0.f,0.f,0.f,0.f};

  const int NT = K >> 5;
  stage(0, 0); stage(1, 32); stage(2, 64);

  int cur = 0;
  for(int t=0; t<NT; ++t){
    if(t+2 < NT){
      if constexpr(LPW==2) asm volatile("s_waitcnt vmcnt(4)" ::: "memory");
      else                 asm volatile("s_waitcnt vmcnt(6)" ::: "memory");
    } else if(t+1 < NT){
      if constexpr(LPW==2) asm volatile("s_waitcnt vmcnt(2)" ::: "memory");
      else                 asm volatile("s_waitcnt vmcnt(3)" ::: "memory");
    } else {
      VMCNT0();
    }
    RBAR();
    bf16x8 af[2], bfr[NBF];
    #pragma unroll
    for(int m=0;m<2;m++) af[m] = *(const bf16x8*)&sA[cur][(wr*2+m)*512 + lane*8];
    #pragma unroll
    for(int n=0;n<NBF;n++) bfr[n] = *(const bf16x8*)&sB[cur][(wc*NBF+n)*512 + lane*8];
    LGKM0();
    RBAR();
    if(t+3 < NT) stage(cur, (t+3)*32);
    #pragma unroll
    for(int m=0;m<2;m++)
      #pragma unroll
      for(int n=0;n<NBF;n++)
        acc[m][n] = __builtin_amdgcn_mfma_f32_16x16x32_bf16(af[m], bfr[n], acc[m][n], 0, 0, 0);
    cur = (cur==2) ? 0 : cur+1;
  }

  const int colb = n0 + wc*(BN/2);
  #pragma unroll
  for(int m=0;m<2;m++){
    int rowb = m0 + wr*32 + m*16 + kq*4;
    #pragma unroll
    for(int n=0;n<NBF;n++){
      int col = colb + n*16 + r16;
      float bv = bias ? bias[col] : 0.f;
      #pragma unroll
      for(int i=0;i<4;i++){
        int row = rowb + i;
        float v = acc[m][n][i] + bv;
        if(qs && col < C_) v *= 0.125f;
        if(act) v = 0.5f*v*(1.f + erff(v*0.70710678118654752f));
        if(resid) v += resid[(size_t)row*N + col];
        if(outB) outB[(size_t)row*N + col] = f2bf(v);
        else outF[(size_t)row*N + col] = v;
      }
    }
  }
}

// ---------------- BM=64 BN=64 BK=64 variant (proj / fc2) ----------------
__global__ __launch_bounds__(256) void gemm_s64k64(
    const ushort_t* __restrict__ A, const ushort_t* __restrict__ W,
    const float* __restrict__ bias, const float* resid,
    float* outF, ushort_t* outB,
    int M, int N, int K)
{
  __shared__ __align__(16) short sA[3][2][4*512];   // [buf][khalf][sub*512+lane*8]
  __shared__ __align__(16) short sB[3][2][4*512];
  const int tid  = threadIdx.x;
  const int lane = tid & 63, wid = tid >> 6;
  const int wr = wid >> 1, wc = wid & 1;
  const int nwg = gridDim.x * gridDim.y;
  const int lid = blockIdx.x + gridDim.x * blockIdx.y;
  const int swz = (lid & 7) * (nwg >> 3) + (lid >> 3);
  const int m0 = (swz % gridDim.x) * 64, n0 = (swz / gridDim.x) * 64;
  const int r16 = lane & 15, kq = lane >> 4;

  auto stage = [&](int buf, int k0){              // 4 loads/wave
    #pragma unroll
    for(int h=0; h<2; ++h){
      const ushort_t* ga = A + (size_t)(m0 + wid*16 + r16)*K + k0 + h*32 + kq*8;
      __builtin_amdgcn_global_load_lds((const AS1 void*)ga,
          (AS3 void*)&sA[buf][h][wid*512], 16, 0, 0);
      const ushort_t* gb = W + (size_t)(n0 + wid*16 + r16)*K + k0 + h*32 + kq*8;
      __builtin_amdgcn_global_load_lds((const AS1 void*)gb,
          (AS3 void*)&sB[buf][h][wid*512], 16, 0, 0);
    }
  };

  f32x4 acc[2][2];
  #pragma unroll
  for(int i=0;i<2;i++)
    #pragma unroll
    for(int j=0;j<2;j++) acc[i][j] = (f32x4){0.f,0.f,0.f,0.f};

  const int NT = K >> 6;              // proj 16, fc2 64
  stage(0, 0); stage(1, 64); stage(2, 128);

  int cur = 0;
  for(int t=0; t<NT; ++t){
    if(t+2 < NT)      asm volatile("s_waitcnt vmcnt(8)" ::: "memory");
    else if(t+1 < NT) asm volatile("s_waitcnt vmcnt(4)" ::: "memory");
    else              VMCNT0();
    RBAR();
    bf16x8 af[2][2], bfr[2][2];       // [ks][m/n]
    #pragma unroll
    for(int ks=0; ks<2; ++ks){
      #pragma unroll
      for(int m=0;m<2;m++) af[ks][m] = *(const bf16x8*)&sA[cur][ks][(wr*2+m)*512 + lane*8];
      #pragma unroll
      for(int n=0;n<2;n++) bfr[ks][n] = *(const bf16x8*)&sB[cur][ks][(wc*2+n)*512 + lane*8];
    }
    LGKM0();
    RBAR();
    if(t+3 < NT) stage(cur, (t+3)*64);
    #pragma unroll
    for(int ks=0; ks<2; ++ks)
      #pragma unroll
      for(int m=0;m<2;m++)
        #pragma unroll
        for(int n=0;n<2;n++)
          acc[m][n] = __builtin_amdgcn_mfma_f32_16x16x32_bf16(af[ks][m], bfr[ks][n], acc[m][n], 0, 0, 0);
    cur = (cur==2) ? 0 : cur+1;
  }

  #pragma unroll
  for(int m=0;m<2;m++){
    int rowb = m0 + wr*32 + m*16 + kq*4;
    #pragma unroll
    for(int n=0;n<2;n++){
      int col = n0 + wc*32 + n*16 + r16;
      float bv = bias ? bias[col] : 0.f;
      #pragma unroll
      for(int i=0;i<4;i++){
        int row = rowb + i;
        float v = acc[m][n][i] + bv;
        if(resid) v += resid[(size_t)row*N + col];
        if(outB) outB[(size_t)row*N + col] = f2bf(v);
        else outF[(size_t)row*N + col] = v;
      }
    }
  }
}

// ---------------- fused flash attention (bf16 MFMA, KVBLK=64, async dbuf) ----------------
__global__ __launch_bounds__(256) void flash_kernel(const ushort_t* __restrict__ qkv,
    ushort_t* __restrict__ y){
  const int tid = threadIdx.x, lane = tid & 63, wid = tid >> 6;
  const int r16 = lane & 15, kq = lane >> 4;
  const int lid = blockIdx.x + 16*blockIdx.y;
  const int swz = (lid & 7)*64 + (lid >> 3);
  const int qt = 15 - (swz & 15), bh = swz >> 4;   // descending-qt (LPT)
  const int b = bh >> 4, h = bh & 15;
  const int q0 = qt*64, qw0 = q0 + wid*16;
  const int qa = qw0 + r16;

  __shared__ __align__(16) short Kt[2][8][512];
  __shared__ __align__(16) short VT[2][64][72];
  __shared__ __align__(16) short Pl[4][16][72];
  __shared__ __align__(16) short Ol[4][16][72];

  const size_t rowQ = (size_t)(b*T_ + qa)*QLD_ + h*64 + kq*8;
  bf16x8 qf0 = *(const bf16x8*)(qkv + rowQ);
  bf16x8 qf1 = *(const bf16x8*)(qkv + rowQ + 32);

  auto stageK = [&](int buf, int jt){
    #pragma unroll
    for(int s2=0;s2<2;s2++){
      int s = wid*2 + s2;
      const ushort_t* g = qkv + (size_t)(b*T_ + jt*64 + (s>>1)*16 + r16)*QLD_
                          + C_ + h*64 + (s&1)*32 + kq*8;
      __builtin_amdgcn_global_load_lds((const AS1 void*)g,
          (AS3 void*)&Kt[buf][s][lane*8], 16, 0, 0);
    }
  };

  f32x4 acc[4];
  #pragma unroll
  for(int t=0;t<4;t++) acc[t] = (f32x4){0.f,0.f,0.f,0.f};
  float m_r = -INFINITY, l_r = 0.f;

  {
    stageK(0, 0);
    const ushort_t* vg = qkv + (size_t)(b*T_ + lane)*QLD_ + 2*C_ + h*64;
    bf16x8 va = *(const bf16x8*)(vg + wid*8);
    bf16x8 vb = *(const bf16x8*)(vg + 32 + wid*8);
    VMCNT0();
    #pragma unroll
    for(int j=0;j<8;j++){ VT[0][wid*8+j][lane]=va[j]; VT[0][32+wid*8+j][lane]=vb[j]; }
    __syncthreads();
  }

  const int njt = qt + 1;
  for(int jt=0; jt<njt; ++jt){
    const int cur = jt & 1;
    const bool more = (jt+1) < njt;
    bf16x8 vr0, vr1;
    if(more){
      stageK(cur^1, jt+1);
      const ushort_t* vg = qkv + (size_t)(b*T_ + (jt+1)*64 + lane)*QLD_ + 2*C_ + h*64;
      vr0 = *(const bf16x8*)(vg + wid*8);
      vr1 = *(const bf16x8*)(vg + 32 + wid*8);
    }

    f32x4 st[4];
    __builtin_amdgcn_s_setprio(1);
    #pragma unroll
    for(int kr=0;kr<4;kr++){
      st[kr] = (f32x4){0.f,0.f,0.f,0.f};
      st[kr] = __builtin_amdgcn_mfma_f32_16x16x32_bf16(*(const bf16x8*)&Kt[cur][kr*2+0][lane*8], qf0, st[kr], 0,0,0);
      st[kr] = __builtin_amdgcn_mfma_f32_16x16x32_bf16(*(const bf16x8*)&Kt[cur][kr*2+1][lane*8], qf1, st[kr], 0,0,0);
    }
    __builtin_amdgcn_s_setprio(0);

    float vals[16];
    if(jt == njt-1){
      #pragma unroll
      for(int kr=0;kr<4;kr++)
        #pragma unroll
        for(int i=0;i<4;i++){
          int ka = jt*64 + kr*16 + 4*kq + i;
          vals[kr*4+i] = (ka <= qa) ? st[kr][i] : -INFINITY;
        }
    } else {
      #pragma unroll
      for(int kr=0;kr<4;kr++)
        #pragma unroll
        for(int i=0;i<4;i++) vals[kr*4+i] = st[kr][i];
    }
    float t8[8];
    #pragma unroll
    for(int i=0;i<8;i++) t8[i] = fmaxf(vals[i], vals[i+8]);
    float t4a = fmaxf(t8[0],t8[4]), t4b = fmaxf(t8[1],t8[5]);
    float t4c = fmaxf(t8[2],t8[6]), t4d = fmaxf(t8[3],t8[7]);
    float pmax = fmaxf(fmaxf(t4a,t4b), fmaxf(t4c,t4d));
    pmax = fmaxf(pmax, __shfl_xor(pmax, 16, 64));
    pmax = fmaxf(pmax, __shfl_xor(pmax, 32, 64));

    if(!__all(pmax - m_r <= 8.f)){
      float mnew = fmaxf(m_r, pmax);
      float alpha = __expf(m_r - mnew);
      l_r *= alpha;
      #pragma unroll
      for(int t=0;t<4;t++)
        #pragma unroll
        for(int j=0;j<4;j++) acc[t][j] *= alpha;
      m_r = mnew;
    }

    float ps = 0.f;
    #pragma unroll
    for(int kr=0;kr<4;kr++){
      float p0 = __expf(vals[kr*4+0]-m_r), p1 = __expf(vals[kr*4+1]-m_r);
      float p2 = __expf(vals[kr*4+2]-m_r), p3 = __expf(vals[kr*4+3]-m_r);
      ps += (p0+p1)+(p2+p3);
      *(unsigned*)&Pl[wid][r16][kr*16 + 4*kq]     = cvtpk_bf16(p0, p1);
      *(unsigned*)&Pl[wid][r16][kr*16 + 4*kq + 2] = cvtpk_bf16(p2, p3);
    }
    ps += __shfl_xor(ps, 16, 64);
    ps += __shfl_xor(ps, 32, 64);
    l_r += ps;

    union { bf16x8 v8; uint2 u2[2]; } pf, vf;
    __builtin_amdgcn_s_setprio(1);
    #pragma unroll
    for(int ks2=0; ks2<2; ks2++){
      pf.u2[0] = *(const uint2*)&Pl[wid][r16][ks2*32 + kq*8];
      pf.u2[1] = *(const uint2*)&Pl[wid][r16][ks2*32 + kq*8 + 4];
      #pragma unroll
      for(int db=0; db<4; db++){
        vf.u2[0] = *(const uint2*)&VT[cur][16*db + r16][ks2*32 + kq*8];
        vf.u2[1] = *(const uint2*)&VT[cur][16*db + r16][ks2*32 + kq*8 + 4];
        acc[db] = __builtin_amdgcn_mfma_f32_16x16x32_bf16(vf.v8, pf.v8, acc[db], 0,0,0);
      }
    }
    __builtin_amdgcn_s_setprio(0);

    if(more){
      VMCNT0();
      #pragma unroll
      for(int j=0;j<8;j++){ VT[cur^1][wid*8+j][lane]=vr0[j]; VT[cur^1][32+wid*8+j][lane]=vr1[j]; }
    }
    __syncthreads();
  }

  float linv = 1.f / l_r;
  #pragma unroll
  for(int db=0; db<4; db++)
    #pragma unroll
    for(int i=0;i<4;i++)
      Ol[wid][r16][16*db + 4*kq + i] = (short)f2bf(acc[db][i]*linv);
  int q = lane >> 2, c0 = (lane & 3)*16;
  const short* src = &Ol[wid][q][c0];
  uint2 a0 = *(const uint2*)(src+0), a1 = *(const uint2*)(src+4);
  uint2 a2 = *(const uint2*)(src+8), a3 = *(const uint2*)(src+12);
  ushort_t* dst = y + (size_t)(b*T_ + qw0 + q)*C_ + h*64 + c0;
  uint4 w0 = {a0.x, a0.y, a1.x, a1.y}, w1 = {a2.x, a2.y, a3.x, a3.y};
  *(uint4*)(dst+0) = w0;
  *(uint4*)(dst+8) = w1;
}

// ---------------- f32 GEMM fallback (head only, if ws too small) ----------------
__global__ __launch_bounds__(256) void gemm_nt(const float* __restrict__ A, const float* __restrict__ W,
    const float* __restrict__ bias, const float* resid, float* Cm,
    int M, int N, int K, int act){
  __shared__ float As[16][68];
  __shared__ float Bs[16][68];
  int m0 = blockIdx.y*64, n0 = blockIdx.x*64;
  int tid = threadIdx.x;
  int tx = tid & 15, ty = tid >> 4;
  float acc[4][4] = {};
  for(int k0=0;k0<K;k0+=16){
    #pragma unroll
    for(int l=0;l<4;l++){
      int li = tid + l*256;
      int r = li >> 4, c = li & 15;
      int gm = m0 + r, gn = n0 + r, gk = k0 + c;
      As[c][r] = (gm<M) ? A[(size_t)gm*K + gk] : 0.f;
      Bs[c][r] = (gn<N) ? W[(size_t)gn*K + gk] : 0.f;
    }
    __syncthreads();
    #pragma unroll
    for(int k=0;k<16;k++){
      float4 av = *(const float4*)&As[k][ty*4];
      float4 bv = *(const float4*)&Bs[k][tx*4];
      float a[4] = {av.x, av.y, av.z, av.w};
      float b4[4] = {bv.x, bv.y, bv.z, bv.w};
      #pragma unroll
      for(int i=0;i<4;i++)
        #pragma unroll
        for(int j=0;j<4;j++)
          acc[i][j] = fmaf(a[i], b4[j], acc[i][j]);
    }
    __syncthreads();
  }
  #pragma unroll
  for(int i=0;i<4;i++){
    int m = m0 + ty*4 + i; if(m>=M) continue;
    #pragma unroll
    for(int j=0;j<4;j++){
      int n = n0 + tx*4 + j; if(n>=N) continue;
      float v = acc[i][j];
      if(bias) v += bias[n];
      if(act)  v = 0.5f*v*(1.f + erff(v*0.70710678118654752f));
      if(resid) v += resid[(size_t)m*N + n];
      Cm[(size_t)m*N + n] = v;
    }
  }
}

extern "C" void kernel_launch(void* const* d_in, const int* in_sizes, int n_in,
                              void* d_out, int out_size, void* d_ws, size_t ws_size,
                              hipStream_t stream) {
  const int*   idx  = (const int*)  d_in[0];
  const float* tok  = (const float*)d_in[1];
  const float* pos  = (const float*)d_in[2];
  const float* Wq   = (const float*)d_in[3];
  const float* bq   = (const float*)d_in[4];
  const float* Wk   = (const float*)d_in[5];
  const float* bk   = (const float*)d_in[6];
  const float* Wv   = (const float*)d_in[7];
  const float* bv   = (const float*)d_in[8];
  const float* Wp   = (const float*)d_in[9];
  const float* bp   = (const float*)d_in[10];
  const float* ln1w = (const float*)d_in[11];
  const float* ln1b = (const float*)d_in[12];
  const float* ln2w = (const float*)d_in[13];
  const float* ln2b = (const float*)d_in[14];
  const float* W1   = (const float*)d_in[15];
  const float* b1   = (const float*)d_in[16];
  const float* W2   = (const float*)d_in[17];
  const float* b2   = (const float*)d_in[18];
  const float* lnfw = (const float*)d_in[19];
  const float* lnfb = (const float*)d_in[20];
  const float* headw= (const float*)d_in[21];

  float* out = (float*)d_out;
  ushort_t* qkvb = (ushort_t*)(out);                  //  6,291,456 bf16
  ushort_t* hb   = (ushort_t*)(out + 3145728);        //  2,097,152 bf16
  ushort_t* yb   = (ushort_t*)(out + 4194304);        //  2,097,152 bf16
  ushort_t* mb   = (ushort_t*)(out + 5242880);        //  8,388,608 bf16
  ushort_t* wqkv = (ushort_t*)(out + 9437184);        // 25,165,824 bf16
  ushort_t* wpb  = (ushort_t*)(out + 22020096);       //  8,388,608 bf16
  ushort_t* w1b  = (ushort_t*)(out + 26214400);       // 33,554,432 bf16
  ushort_t* w2b  = (ushort_t*)(out + 42991616);       // 33,554,432 bf16
  float*    bqkv = out + 59768832;                    //     24,576 f
  float*    x    = (float*)d_ws;
  ushort_t* xb   = (ushort_t*)((float*)d_ws + 2097152);
  ushort_t* whb  = (ushort_t*)((float*)d_ws + 3145728);
  const bool big = ws_size >= (size_t)28877312 * 4;

  cvt_all<<<4096,256,0,stream>>>(Wq, Wk, Wv, Wp, W1, W2, headw,
      wqkv, wpb, w1b, w2b, whb, big ? (long)V_*C_/4 : 0);
  pack_qkv_bias<<<L_*QLD_/256,256,0,stream>>>(bq, bk, bv, bqkv);

  embed_kernel<<<BT_*C_/256, 256, 0, stream>>>(idx, tok, pos, x);

  for(int l=0;l<L_;l++){
    ln_kernel<<<BT_,256,0,stream>>>(x, ln1w + l*C_, ln1b + l*C_, nullptr, hb);
    gemm_s64<128><<<dim3(BT_/64, QLD_/128),256,0,stream>>>(hb, wqkv + (size_t)l*3*CC_,
        bqkv + l*QLD_, nullptr, nullptr, qkvb, BT_, QLD_, C_, 0, 1);
    flash_kernel<<<dim3(T_/64, B_*H_),256,0,stream>>>(qkvb, yb);
    gemm_s64k64<<<dim3(BT_/64, C_/64),256,0,stream>>>(yb, wpb + (size_t)l*CC_,
        bp + l*C_, x, x, nullptr, BT_, C_, C_);
    ln_kernel<<<BT_,256,0,stream>>>(x, ln2w + l*C_, ln2b + l*C_, nullptr, hb);
    gemm_s64<128><<<dim3(BT_/64, 4*C_/128),256,0,stream>>>(hb, w1b + (size_t)l*4*CC_,
        b1 + (size_t)l*4*C_, nullptr, nullptr, mb, BT_, 4*C_, C_, 1, 0);
    gemm_s64k64<<<dim3(BT_/64, C_/64),256,0,stream>>>(mb, w2b + (size_t)l*4*CC_,
        b2 + l*C_, x, x, nullptr, BT_, C_, 4*C_);
  }

  if(big){
    ln_kernel<<<BT_,256,0,stream>>>(x, lnfw, lnfb, nullptr, xb);
    gemm_mfma<128><<<dim3(BT_/128, (V_+127)/128),256,0,stream>>>(xb, whb,
        nullptr, nullptr, out, nullptr, BT_, V_, C_, 0, 1, 0);
  } else {
    ln_kernel<<<BT_,256,0,stream>>>(x, lnfw, lnfb, x, nullptr);
    gemm_nt<<<dim3((V_+63)/64, BT_/64),256,0,stream>>>(x, headw, nullptr, nullptr, out,
                                                       BT_, V_, C_, 0);
  }
}